// Round 1
// baseline (5332.442 us; speedup 1.0000x reference)
//
#include <hip/hip_runtime.h>

// SpMM: out[b, r, :] += values[e] * feat[b, c, :]  for each COO edge e=(r,c)
// N=50000, NNZ=1.6M, B=2, D=128, fp32.
// Baseline: 32 lanes per edge, float4 per lane (32*4 = 128 = D),
// both batches handled by the same lane group; scatter via atomicAdd.

#define FEAT_D 128

__global__ void __launch_bounds__(256) spmm_atomic_kernel(
    const int* __restrict__ indices,   // [2, nnz]: rows then cols
    const float* __restrict__ values,  // [nnz]
    const int* __restrict__ n_ptr,     // scalar n on device
    const float* __restrict__ feat,    // [B, n, D]
    float* __restrict__ out,           // [B, n, D]
    int nnz) {
  const int n = n_ptr[0];
  const long long gid = (long long)blockIdx.x * blockDim.x + threadIdx.x;
  const int lane = (int)(gid & 31);          // 32 lanes per edge
  const long long e = gid >> 5;
  if (e >= nnz) return;

  const int r = indices[e];
  const int c = indices[(long long)nnz + e];
  const float v = values[e];

  const size_t batch_stride = (size_t)n * FEAT_D;

  // batch 0
  {
    const float4 a = *(reinterpret_cast<const float4*>(feat + (size_t)c * FEAT_D) + lane);
    float* dst = out + (size_t)r * FEAT_D + (size_t)lane * 4;
    atomicAdd(dst + 0, v * a.x);
    atomicAdd(dst + 1, v * a.y);
    atomicAdd(dst + 2, v * a.z);
    atomicAdd(dst + 3, v * a.w);
  }
  // batch 1
  {
    const float4 a = *(reinterpret_cast<const float4*>(feat + batch_stride + (size_t)c * FEAT_D) + lane);
    float* dst = out + batch_stride + (size_t)r * FEAT_D + (size_t)lane * 4;
    atomicAdd(dst + 0, v * a.x);
    atomicAdd(dst + 1, v * a.y);
    atomicAdd(dst + 2, v * a.z);
    atomicAdd(dst + 3, v * a.w);
  }
}

extern "C" void kernel_launch(void* const* d_in, const int* in_sizes, int n_in,
                              void* d_out, int out_size, void* d_ws, size_t ws_size,
                              hipStream_t stream) {
  const int*   indices = (const int*)d_in[0];    // [2, nnz] int32
  const float* values  = (const float*)d_in[1];  // [nnz] f32
  const int*   n_ptr   = (const int*)d_in[2];    // scalar
  const float* feat    = (const float*)d_in[3];  // [B, n, D] f32
  float*       out     = (float*)d_out;          // [B, n, D] f32

  const int nnz = in_sizes[1];

  // Output accumulates via atomics: must start from zero every call
  // (harness poisons d_out once and never re-poisons between replays).
  hipMemsetAsync(d_out, 0, (size_t)out_size * sizeof(float), stream);

  const long long total_threads = (long long)nnz * 32;
  const int block = 256;
  const unsigned grid = (unsigned)((total_threads + block - 1) / block);
  spmm_atomic_kernel<<<grid, block, 0, stream>>>(indices, values, n_ptr, feat, out, nnz);
}

// Round 2
// 531.275 us; speedup vs baseline: 10.0371x; 10.0371x over previous
//
#include <hip/hip_runtime.h>

// SpMM out[b,r,:] += v[e] * feat[b, c(e), :], COO, N=50000, NNZ=1.6M, B=2, D=128 fp32.
// Strategy: counting-sort edges by row in d_ws, then segment-reduce with one
// 64-lane wave per row (lanes 0-31 -> batch 0, lanes 32-63 -> batch 1,
// float4 per lane). Output written exactly once -> no fp32 atomics.

#define FEAT_D 128
#define BATCH 2

// ---------- phase 1: histogram of rows ----------
__global__ void hist_kernel(const int* __restrict__ rows, int nnz,
                            int* __restrict__ counts) {
  for (int e = blockIdx.x * blockDim.x + threadIdx.x; e < nnz;
       e += gridDim.x * blockDim.x) {
    atomicAdd(&counts[rows[e]], 1);
  }
}

// ---------- phase 2: exclusive scan over n counts (single block) ----------
__global__ void __launch_bounds__(1024) scan_kernel(
    const int* __restrict__ counts, int* __restrict__ offsets,
    int* __restrict__ cursor, int n) {
  __shared__ int lds[1024];
  const int t = threadIdx.x;
  const int C = (n + 1023) >> 10;  // chunk per thread
  const int lo = t * C;
  const int hi = min(lo + C, n);
  int s = 0;
  for (int i = lo; i < hi; ++i) s += counts[i];
  lds[t] = s;
  __syncthreads();
  // Kogge-Stone inclusive scan over 1024 partials
  for (int off = 1; off < 1024; off <<= 1) {
    int v = (t >= off) ? lds[t - off] : 0;
    __syncthreads();
    lds[t] += v;
    __syncthreads();
  }
  int run = (t == 0) ? 0 : lds[t - 1];
  for (int i = lo; i < hi; ++i) {
    offsets[i] = run;
    cursor[i] = run;
    run += counts[i];
  }
  if (t == 1023) offsets[n] = lds[1023];  // == nnz
}

// ---------- phase 3: scatter edges into row-sorted order ----------
__global__ void scatter_kernel(const int* __restrict__ rows,
                               const int* __restrict__ cols,
                               const float* __restrict__ vals, int nnz,
                               int* __restrict__ cursor,
                               unsigned long long* __restrict__ cv) {
  for (int e = blockIdx.x * blockDim.x + threadIdx.x; e < nnz;
       e += gridDim.x * blockDim.x) {
    const int r = rows[e];
    const int pos = atomicAdd(&cursor[r], 1);
    const unsigned long long p =
        ((unsigned long long)__float_as_uint(vals[e]) << 32) |
        (unsigned int)cols[e];
    cv[pos] = p;
  }
}

// ---------- phase 4: segment reduce, one wave per row ----------
__global__ void __launch_bounds__(256) spmm_seg_kernel(
    const int* __restrict__ offsets,
    const unsigned long long* __restrict__ cv,
    const float* __restrict__ feat, float* __restrict__ out, int n) {
  const int wid = (int)((blockIdx.x * (unsigned)blockDim.x + threadIdx.x) >> 6);
  if (wid >= n) return;
  const int lane = threadIdx.x & 63;
  const int half = lane >> 5;   // 0 -> batch 0, 1 -> batch 1
  const int l32 = lane & 31;    // float4 slot within the row

  int start = offsets[wid];
  int end = offsets[wid + 1];
  start = __builtin_amdgcn_readfirstlane(start);
  end = __builtin_amdgcn_readfirstlane(end);

  const size_t bs = (size_t)n * FEAT_D;  // batch stride in floats
  const float* fbase = feat + (size_t)half * bs + (size_t)l32 * 4;

  float4 acc = make_float4(0.f, 0.f, 0.f, 0.f);
#pragma unroll 4
  for (int i = start; i < end; ++i) {
    const unsigned long long p = cv[i];
    const int c = (int)(unsigned int)(p & 0xffffffffu);
    const float v = __uint_as_float((unsigned int)(p >> 32));
    const float4 x = *reinterpret_cast<const float4*>(fbase + (size_t)c * FEAT_D);
    acc.x += v * x.x;
    acc.y += v * x.y;
    acc.z += v * x.z;
    acc.w += v * x.w;
  }
  float* dst = out + (size_t)half * bs + (size_t)wid * FEAT_D + (size_t)l32 * 4;
  *reinterpret_cast<float4*>(dst) = acc;
}

// ---------- fallback (ws too small): atomic scatter ----------
__global__ void __launch_bounds__(256) spmm_atomic_kernel(
    const int* __restrict__ indices, const float* __restrict__ values,
    const float* __restrict__ feat, float* __restrict__ out, int nnz, int n) {
  const long long gid = (long long)blockIdx.x * blockDim.x + threadIdx.x;
  const int lane = (int)(gid & 31);
  const long long e = gid >> 5;
  if (e >= nnz) return;
  const int r = indices[e];
  const int c = indices[(long long)nnz + e];
  const float v = values[e];
  const size_t bs = (size_t)n * FEAT_D;
  for (int b = 0; b < BATCH; ++b) {
    const float4 a = *(reinterpret_cast<const float4*>(feat + b * bs + (size_t)c * FEAT_D) + lane);
    float* dst = out + b * bs + (size_t)r * FEAT_D + (size_t)lane * 4;
    atomicAdd(dst + 0, v * a.x);
    atomicAdd(dst + 1, v * a.y);
    atomicAdd(dst + 2, v * a.z);
    atomicAdd(dst + 3, v * a.w);
  }
}

extern "C" void kernel_launch(void* const* d_in, const int* in_sizes, int n_in,
                              void* d_out, int out_size, void* d_ws, size_t ws_size,
                              hipStream_t stream) {
  const int* indices = (const int*)d_in[0];   // [2, nnz]
  const float* values = (const float*)d_in[1];// [nnz]
  const float* feat = (const float*)d_in[3];  // [B, n, D]
  float* out = (float*)d_out;

  const int nnz = in_sizes[1];
  const int n = out_size / (BATCH * FEAT_D);  // out = [B, n, D]

  const int* rows = indices;
  const int* cols = indices + nnz;

  // workspace layout (ints then 8B-aligned cv)
  size_t off_offsets = 0;                                // (n+1) ints
  size_t off_cursor = off_offsets + (size_t)(n + 1) * 4; // n ints
  size_t off_counts = off_cursor + (size_t)n * 4;        // n ints
  size_t off_cv = (off_counts + (size_t)n * 4 + 255) & ~(size_t)255;  // nnz * 8B
  size_t need = off_cv + (size_t)nnz * 8;

  if (ws_size < need) {
    // fallback: atomic scatter (correct, slower)
    hipMemsetAsync(d_out, 0, (size_t)out_size * sizeof(float), stream);
    const long long total_threads = (long long)nnz * 32;
    const unsigned grid = (unsigned)((total_threads + 255) / 256);
    spmm_atomic_kernel<<<grid, 256, 0, stream>>>(indices, values, feat, out, nnz, n);
    return;
  }

  char* ws = (char*)d_ws;
  int* offsets = (int*)(ws + off_offsets);
  int* cursor = (int*)(ws + off_cursor);
  int* counts = (int*)(ws + off_counts);
  unsigned long long* cv = (unsigned long long*)(ws + off_cv);

  hipMemsetAsync(counts, 0, (size_t)n * 4, stream);

  hist_kernel<<<2048, 256, 0, stream>>>(rows, nnz, counts);
  scan_kernel<<<1, 1024, 0, stream>>>(counts, offsets, cursor, n);
  scatter_kernel<<<2048, 256, 0, stream>>>(rows, cols, values, nnz, cursor, cv);

  const long long waves = n;  // one wave per row
  const long long threads = waves * 64;
  const unsigned grid = (unsigned)((threads + 255) / 256);
  spmm_seg_kernel<<<grid, 256, 0, stream>>>(offsets, cv, feat, out, n);
}

// Round 3
// 427.877 us; speedup vs baseline: 12.4626x; 1.2417x over previous
//
#include <hip/hip_runtime.h>

// SpMM out[b,r,:] += v[e] * feat[b, c(e), :], COO, N=50000, NNZ=1.6M, B=2, D=128 fp32.
// Pipeline: hist -> scan -> scatter (counting sort by row) ; feat packed to
// bf16 [n][B][D] so one edge gather = one contiguous 512B read for both
// batches ; segment-reduce one wave per row, fp32 accumulate, exact-once store.

#define FEAT_D 128
#define BATCH 2

__device__ inline unsigned short f32_to_bf16_rne(float f) {
  unsigned u = __float_as_uint(f);
  unsigned r = u + 0x7fffu + ((u >> 16) & 1u);
  return (unsigned short)(r >> 16);
}

// ---------- histogram of rows (int4-vectorized) ----------
__global__ void hist_kernel(const int* __restrict__ rows, int nnz,
                            int* __restrict__ counts) {
  const int n4 = nnz >> 2;
  for (int i = blockIdx.x * blockDim.x + threadIdx.x; i < n4;
       i += gridDim.x * blockDim.x) {
    const int4 r4 = *reinterpret_cast<const int4*>(rows + (size_t)i * 4);
    atomicAdd(&counts[r4.x], 1);
    atomicAdd(&counts[r4.y], 1);
    atomicAdd(&counts[r4.z], 1);
    atomicAdd(&counts[r4.w], 1);
  }
  // tail
  if (blockIdx.x == 0 && threadIdx.x < (nnz & 3)) {
    atomicAdd(&counts[rows[(n4 << 2) + threadIdx.x]], 1);
  }
}

// ---------- exclusive scan over n counts (single block) ----------
__global__ void __launch_bounds__(1024) scan_kernel(
    const int* __restrict__ counts, int* __restrict__ offsets,
    int* __restrict__ cursor, int n) {
  __shared__ int lds[1024];
  const int t = threadIdx.x;
  const int C = (n + 1023) >> 10;
  const int lo = t * C;
  const int hi = min(lo + C, n);
  int s = 0;
  for (int i = lo; i < hi; ++i) s += counts[i];
  lds[t] = s;
  __syncthreads();
  for (int off = 1; off < 1024; off <<= 1) {
    int v = (t >= off) ? lds[t - off] : 0;
    __syncthreads();
    lds[t] += v;
    __syncthreads();
  }
  int run = (t == 0) ? 0 : lds[t - 1];
  for (int i = lo; i < hi; ++i) {
    offsets[i] = run;
    cursor[i] = run;
    run += counts[i];
  }
  if (t == 1023) offsets[n] = lds[1023];
}

// ---------- scatter edges into row-sorted order (vectorized loads) ----------
__global__ void scatter_kernel(const int* __restrict__ rows,
                               const int* __restrict__ cols,
                               const float* __restrict__ vals, int nnz,
                               int* __restrict__ cursor,
                               unsigned long long* __restrict__ cv) {
  const int n4 = nnz >> 2;
  for (int i = blockIdx.x * blockDim.x + threadIdx.x; i < n4;
       i += gridDim.x * blockDim.x) {
    const int4 r4 = *reinterpret_cast<const int4*>(rows + (size_t)i * 4);
    const int4 c4 = *reinterpret_cast<const int4*>(cols + (size_t)i * 4);
    const float4 v4 = *reinterpret_cast<const float4*>(vals + (size_t)i * 4);
    int pos;
    pos = atomicAdd(&cursor[r4.x], 1);
    cv[pos] = ((unsigned long long)__float_as_uint(v4.x) << 32) | (unsigned)c4.x;
    pos = atomicAdd(&cursor[r4.y], 1);
    cv[pos] = ((unsigned long long)__float_as_uint(v4.y) << 32) | (unsigned)c4.y;
    pos = atomicAdd(&cursor[r4.z], 1);
    cv[pos] = ((unsigned long long)__float_as_uint(v4.z) << 32) | (unsigned)c4.z;
    pos = atomicAdd(&cursor[r4.w], 1);
    cv[pos] = ((unsigned long long)__float_as_uint(v4.w) << 32) | (unsigned)c4.w;
  }
  if (blockIdx.x == 0 && threadIdx.x < (nnz & 3)) {
    const int e = (n4 << 2) + threadIdx.x;
    const int pos = atomicAdd(&cursor[rows[e]], 1);
    cv[pos] = ((unsigned long long)__float_as_uint(vals[e]) << 32) | (unsigned)cols[e];
  }
}

// ---------- pack feat [B][n][D] f32 -> [n][B][D] bf16 ----------
__global__ void __launch_bounds__(256) pack_kernel(
    const float* __restrict__ feat, unsigned short* __restrict__ packed, int n) {
  const int q = blockIdx.x * blockDim.x + threadIdx.x;  // quad index
  const int total = n * (BATCH * FEAT_D / 4);           // n * 64
  if (q >= total) return;
  const int r = q >> 6;
  const int rem = q & 63;
  const int b = rem >> 5;
  const int d4 = rem & 31;
  const float4 x = *reinterpret_cast<const float4*>(
      feat + ((size_t)b * n + r) * FEAT_D + (size_t)d4 * 4);
  unsigned a0 = (unsigned)f32_to_bf16_rne(x.x) | ((unsigned)f32_to_bf16_rne(x.y) << 16);
  unsigned a1 = (unsigned)f32_to_bf16_rne(x.z) | ((unsigned)f32_to_bf16_rne(x.w) << 16);
  *reinterpret_cast<uint2*>(packed + (size_t)q * 4) = make_uint2(a0, a1);
}

// ---------- segment reduce (bf16 packed), one wave per row ----------
__global__ void __launch_bounds__(256) spmm_seg_bf16_kernel(
    const int* __restrict__ offsets,
    const unsigned long long* __restrict__ cv,
    const unsigned short* __restrict__ packed,
    float* __restrict__ out, int n) {
  const int wid = (int)((blockIdx.x * (unsigned)blockDim.x + threadIdx.x) >> 6);
  if (wid >= n) return;
  const int lane = threadIdx.x & 63;

  int start = __builtin_amdgcn_readfirstlane(offsets[wid]);
  int end = __builtin_amdgcn_readfirstlane(offsets[wid + 1]);

  // lane l covers 4 elements at row-offset l*4 of the packed [B*D] row
  const unsigned short* pbase = packed + (size_t)lane * 4;

  float4 acc = make_float4(0.f, 0.f, 0.f, 0.f);
#pragma unroll 4
  for (int i = start; i < end; ++i) {
    const unsigned long long p = cv[i];
    const int c = (int)(unsigned)(p & 0xffffffffu);
    const float v = __uint_as_float((unsigned)(p >> 32));
    const uint2 w = *reinterpret_cast<const uint2*>(pbase + (size_t)c * (BATCH * FEAT_D));
    const float x0 = __uint_as_float(w.x << 16);
    const float x1 = __uint_as_float(w.x & 0xffff0000u);
    const float x2 = __uint_as_float(w.y << 16);
    const float x3 = __uint_as_float(w.y & 0xffff0000u);
    acc.x += v * x0;
    acc.y += v * x1;
    acc.z += v * x2;
    acc.w += v * x3;
  }
  const int half = lane >> 5;
  const int l32 = lane & 31;
  const size_t bs = (size_t)n * FEAT_D;
  float* dst = out + (size_t)half * bs + (size_t)wid * FEAT_D + (size_t)l32 * 4;
  *reinterpret_cast<float4*>(dst) = acc;
}

// ---------- segment reduce (fp32, mid-tier fallback) ----------
__global__ void __launch_bounds__(256) spmm_seg_kernel(
    const int* __restrict__ offsets,
    const unsigned long long* __restrict__ cv,
    const float* __restrict__ feat, float* __restrict__ out, int n) {
  const int wid = (int)((blockIdx.x * (unsigned)blockDim.x + threadIdx.x) >> 6);
  if (wid >= n) return;
  const int lane = threadIdx.x & 63;
  const int half = lane >> 5;
  const int l32 = lane & 31;
  int start = __builtin_amdgcn_readfirstlane(offsets[wid]);
  int end = __builtin_amdgcn_readfirstlane(offsets[wid + 1]);
  const size_t bs = (size_t)n * FEAT_D;
  const float* fbase = feat + (size_t)half * bs + (size_t)l32 * 4;
  float4 acc = make_float4(0.f, 0.f, 0.f, 0.f);
#pragma unroll 4
  for (int i = start; i < end; ++i) {
    const unsigned long long p = cv[i];
    const int c = (int)(unsigned)(p & 0xffffffffu);
    const float v = __uint_as_float((unsigned)(p >> 32));
    const float4 x = *reinterpret_cast<const float4*>(fbase + (size_t)c * FEAT_D);
    acc.x += v * x.x;
    acc.y += v * x.y;
    acc.z += v * x.z;
    acc.w += v * x.w;
  }
  float* dst = out + (size_t)half * bs + (size_t)wid * FEAT_D + (size_t)l32 * 4;
  *reinterpret_cast<float4*>(dst) = acc;
}

// ---------- last-resort fallback: atomic scatter ----------
__global__ void __launch_bounds__(256) spmm_atomic_kernel(
    const int* __restrict__ indices, const float* __restrict__ values,
    const float* __restrict__ feat, float* __restrict__ out, int nnz, int n) {
  const long long gid = (long long)blockIdx.x * blockDim.x + threadIdx.x;
  const int lane = (int)(gid & 31);
  const long long e = gid >> 5;
  if (e >= nnz) return;
  const int r = indices[e];
  const int c = indices[(long long)nnz + e];
  const float v = values[e];
  const size_t bs = (size_t)n * FEAT_D;
  for (int b = 0; b < BATCH; ++b) {
    const float4 a = *(reinterpret_cast<const float4*>(feat + b * bs + (size_t)c * FEAT_D) + lane);
    float* dst = out + b * bs + (size_t)r * FEAT_D + (size_t)lane * 4;
    atomicAdd(dst + 0, v * a.x);
    atomicAdd(dst + 1, v * a.y);
    atomicAdd(dst + 2, v * a.z);
    atomicAdd(dst + 3, v * a.w);
  }
}

extern "C" void kernel_launch(void* const* d_in, const int* in_sizes, int n_in,
                              void* d_out, int out_size, void* d_ws, size_t ws_size,
                              hipStream_t stream) {
  const int* indices = (const int*)d_in[0];
  const float* values = (const float*)d_in[1];
  const float* feat = (const float*)d_in[3];
  float* out = (float*)d_out;

  const int nnz = in_sizes[1];
  const int n = out_size / (BATCH * FEAT_D);

  const int* rows = indices;
  const int* cols = indices + nnz;

  // workspace layout
  size_t off_offsets = 0;
  size_t off_cursor = off_offsets + (size_t)(n + 1) * 4;
  size_t off_counts = off_cursor + (size_t)n * 4;
  size_t off_cv = (off_counts + (size_t)n * 4 + 255) & ~(size_t)255;
  size_t off_packed = (off_cv + (size_t)nnz * 8 + 255) & ~(size_t)255;
  size_t need_sort = off_packed;
  size_t need_full = off_packed + (size_t)n * BATCH * FEAT_D * 2;

  if (ws_size < need_sort) {
    hipMemsetAsync(d_out, 0, (size_t)out_size * sizeof(float), stream);
    const long long total_threads = (long long)nnz * 32;
    const unsigned grid = (unsigned)((total_threads + 255) / 256);
    spmm_atomic_kernel<<<grid, 256, 0, stream>>>(indices, values, feat, out, nnz, n);
    return;
  }

  char* ws = (char*)d_ws;
  int* offsets = (int*)(ws + off_offsets);
  int* cursor = (int*)(ws + off_cursor);
  int* counts = (int*)(ws + off_counts);
  unsigned long long* cv = (unsigned long long*)(ws + off_cv);
  unsigned short* packed = (unsigned short*)(ws + off_packed);

  hipMemsetAsync(counts, 0, (size_t)n * 4, stream);

  const int edge_blocks = (nnz / 4 + 255) / 256;
  hist_kernel<<<min(edge_blocks, 2048), 256, 0, stream>>>(rows, nnz, counts);

  if (ws_size >= need_full) {
    const int pack_total = n * (BATCH * FEAT_D / 4);
    pack_kernel<<<(pack_total + 255) / 256, 256, 0, stream>>>(feat, packed, n);
  }

  scan_kernel<<<1, 1024, 0, stream>>>(counts, offsets, cursor, n);
  scatter_kernel<<<min(edge_blocks, 2048), 256, 0, stream>>>(rows, cols, values, nnz, cursor, cv);

  const unsigned seg_grid = (unsigned)(((long long)n * 64 + 255) / 256);
  if (ws_size >= need_full) {
    spmm_seg_bf16_kernel<<<seg_grid, 256, 0, stream>>>(offsets, cv, packed, out, n);
  } else {
    spmm_seg_kernel<<<seg_grid, 256, 0, stream>>>(offsets, cv, feat, out, n);
  }
}

// Round 4
// 193.801 us; speedup vs baseline: 27.5151x; 2.2078x over previous
//
#include <hip/hip_runtime.h>

// SpMM out[b,r,:] += v[e] * feat[b, c(e), :], COO, N=50000, NNZ=1.6M, B=2, D=128 fp32.
// Pipeline:
//   1. hist_bucket   : 196 coarse buckets (row>>8), LDS-local hist
//   2. scan_buckets  : 196-entry scan -> bucket_base / gcursor
//   3. partition     : LDS-staged scatter into bucket-grouped order (coalesced runs)
//   4. bucket_sort   : per-bucket 256-row counting sort, scatter within L2-hot 64KB window
//   5. pack          : feat [B][n][D] f32 -> [n][B][D] bf16 (one 512B row per edge gather)
//   6. seg reduce    : one wave per row, fp32 accumulate, exact-once store
// cvb (bucket-grouped edges) aliases the packed region; pack runs after bucket_sort.

#define FEAT_D 128
#define BATCH 2
#define RB_SHIFT 8              // 256 rows per bucket
#define PART_E 8192             // edges per partition block
#define PART_T 512              // threads per partition block

__device__ inline unsigned short f32_to_bf16_rne(float f) {
  unsigned u = __float_as_uint(f);
  unsigned r = u + 0x7fffu + ((u >> 16) & 1u);
  return (unsigned short)(r >> 16);
}

// ---------- 1. coarse bucket histogram ----------
__global__ void __launch_bounds__(256) hist_bucket_kernel(
    const int* __restrict__ rows, int nnz, int* __restrict__ bcnt) {
  __shared__ int h[256];
  h[threadIdx.x] = 0;
  __syncthreads();
  for (int i = blockIdx.x * blockDim.x + threadIdx.x; i < nnz;
       i += gridDim.x * blockDim.x)
    atomicAdd(&h[rows[i] >> RB_SHIFT], 1);
  __syncthreads();
  if (h[threadIdx.x]) atomicAdd(&bcnt[threadIdx.x], h[threadIdx.x]);
}

// ---------- 2. scan 196 bucket counts ----------
__global__ void __launch_bounds__(256) scan_buckets_kernel(
    const int* __restrict__ bcnt, int nb, int nnz,
    int* __restrict__ bucket_base, int* __restrict__ gcursor,
    int* __restrict__ offsets, int n) {
  __shared__ int sc[256];
  const int tid = threadIdx.x;
  const int v = (tid < nb) ? bcnt[tid] : 0;
  sc[tid] = v;
  __syncthreads();
  for (int off = 1; off < 256; off <<= 1) {
    int t = (tid >= off) ? sc[tid - off] : 0;
    __syncthreads();
    sc[tid] += t;
    __syncthreads();
  }
  const int excl = sc[tid] - v;
  if (tid < nb) {
    bucket_base[tid] = excl;
    gcursor[tid] = excl;
  }
  if (tid == 0) {
    bucket_base[nb] = nnz;
    offsets[n] = nnz;
  }
}

// ---------- 3. partition into bucket-grouped order (LDS staging) ----------
__global__ void __launch_bounds__(PART_T) partition_kernel(
    const int* __restrict__ rows, const int* __restrict__ cols,
    const float* __restrict__ vals, int nnz, int nb,
    int* __restrict__ gcursor,
    unsigned long long* __restrict__ cvb) {  // (meta = (r&255)<<16 | col, val)
  __shared__ int hist[256];
  __shared__ int excl[256];
  __shared__ int cur[256];
  __shared__ int gdst[256];
  __shared__ unsigned long long stage[PART_E];
  __shared__ unsigned char slotb[PART_E];

  const int tid = threadIdx.x;
  const int base = blockIdx.x * PART_E;
  const int cnt = min(PART_E, nnz - base);

  if (tid < 256) hist[tid] = 0;
  __syncthreads();

  for (int k = tid; k < cnt; k += PART_T)
    atomicAdd(&hist[rows[base + k] >> RB_SHIFT], 1);
  __syncthreads();

  if (tid < 256) excl[tid] = hist[tid];
  __syncthreads();
  for (int off = 1; off < 256; off <<= 1) {
    int v = 0;
    if (tid < 256 && tid >= off) v = excl[tid - off];
    __syncthreads();
    if (tid < 256) excl[tid] += v;
    __syncthreads();
  }
  if (tid < 256) {
    const int e = excl[tid] - hist[tid];  // exclusive
    excl[tid] = e;
    cur[tid] = e;
    int gd = 0;
    if (tid < nb && hist[tid] > 0) {
      const int gb = atomicAdd(&gcursor[tid], hist[tid]);
      gd = gb - e;
    }
    gdst[tid] = gd;
  }
  __syncthreads();

  for (int k = tid; k < cnt; k += PART_T) {
    const int e = base + k;
    const int r = rows[e];
    const int c = cols[e];
    const float v = vals[e];
    const int b = r >> RB_SHIFT;
    const int pos = atomicAdd(&cur[b], 1);
    stage[pos] = ((unsigned long long)__float_as_uint(v) << 32) |
                 (unsigned)(((r & 255) << 16) | c);
    slotb[pos] = (unsigned char)b;
  }
  __syncthreads();

  for (int i = tid; i < cnt; i += PART_T) {
    const int b = slotb[i];
    cvb[gdst[b] + i] = stage[i];
  }
}

// ---------- 4. per-bucket counting sort by row ----------
__global__ void __launch_bounds__(256) bucket_sort_kernel(
    const unsigned long long* __restrict__ cvb,
    const int* __restrict__ bucket_base,
    int* __restrict__ offsets,
    unsigned long long* __restrict__ cv,  // ((val)<<32 | col), row-sorted
    int n) {
  __shared__ int hist[256];
  __shared__ int sc[256];
  __shared__ int cur[256];
  const int tid = threadIdx.x;
  const int b = blockIdx.x;
  const int start = bucket_base[b];
  const int end = bucket_base[b + 1];

  hist[tid] = 0;
  __syncthreads();
  for (int i = start + tid; i < end; i += 256) {
    const unsigned meta = (unsigned)cvb[i];
    atomicAdd(&hist[meta >> 16], 1);
  }
  __syncthreads();
  sc[tid] = hist[tid];
  __syncthreads();
  for (int off = 1; off < 256; off <<= 1) {
    int t = (tid >= off) ? sc[tid - off] : 0;
    __syncthreads();
    sc[tid] += t;
    __syncthreads();
  }
  const int exclv = sc[tid] - hist[tid];
  const int row = (b << RB_SHIFT) + tid;
  if (row < n) offsets[row] = start + exclv;
  cur[tid] = start + exclv;
  __syncthreads();
  for (int i = start + tid; i < end; i += 256) {
    const unsigned long long mv = cvb[i];
    const unsigned meta = (unsigned)mv;
    const int rl = meta >> 16;
    const int pos = atomicAdd(&cur[rl], 1);
    cv[pos] = (mv & 0xffffffff00000000ull) | (unsigned long long)(meta & 0xffffu);
  }
}

// ---------- 5. pack feat [B][n][D] f32 -> [n][B][D] bf16 ----------
__global__ void __launch_bounds__(256) pack_kernel(
    const float* __restrict__ feat, unsigned short* __restrict__ packed, int n) {
  const int q = blockIdx.x * blockDim.x + threadIdx.x;
  const int total = n * (BATCH * FEAT_D / 4);
  if (q >= total) return;
  const int r = q >> 6;
  const int rem = q & 63;
  const int b = rem >> 5;
  const int d4 = rem & 31;
  const float4 x = *reinterpret_cast<const float4*>(
      feat + ((size_t)b * n + r) * FEAT_D + (size_t)d4 * 4);
  unsigned a0 = (unsigned)f32_to_bf16_rne(x.x) | ((unsigned)f32_to_bf16_rne(x.y) << 16);
  unsigned a1 = (unsigned)f32_to_bf16_rne(x.z) | ((unsigned)f32_to_bf16_rne(x.w) << 16);
  *reinterpret_cast<uint2*>(packed + (size_t)q * 4) = make_uint2(a0, a1);
}

// ---------- 6. segment reduce (bf16 packed), one wave per row ----------
__global__ void __launch_bounds__(256) spmm_seg_bf16_kernel(
    const int* __restrict__ offsets,
    const unsigned long long* __restrict__ cv,
    const unsigned short* __restrict__ packed,
    float* __restrict__ out, int n) {
  const int wid = (int)((blockIdx.x * (unsigned)blockDim.x + threadIdx.x) >> 6);
  if (wid >= n) return;
  const int lane = threadIdx.x & 63;

  int start = __builtin_amdgcn_readfirstlane(offsets[wid]);
  int end = __builtin_amdgcn_readfirstlane(offsets[wid + 1]);

  const unsigned short* pbase = packed + (size_t)lane * 4;

  float4 acc = make_float4(0.f, 0.f, 0.f, 0.f);
#pragma unroll 4
  for (int i = start; i < end; ++i) {
    const unsigned long long p = cv[i];
    const int c = (int)(unsigned)(p & 0xffffffffu);
    const float v = __uint_as_float((unsigned)(p >> 32));
    const uint2 w = *reinterpret_cast<const uint2*>(pbase + (size_t)c * (BATCH * FEAT_D));
    const float x0 = __uint_as_float(w.x << 16);
    const float x1 = __uint_as_float(w.x & 0xffff0000u);
    const float x2 = __uint_as_float(w.y << 16);
    const float x3 = __uint_as_float(w.y & 0xffff0000u);
    acc.x += v * x0;
    acc.y += v * x1;
    acc.z += v * x2;
    acc.w += v * x3;
  }
  const int half = lane >> 5;
  const int l32 = lane & 31;
  const size_t bs = (size_t)n * FEAT_D;
  float* dst = out + (size_t)half * bs + (size_t)wid * FEAT_D + (size_t)l32 * 4;
  *reinterpret_cast<float4*>(dst) = acc;
}

// ---------- fallback: atomic scatter (only if ws too small / n too big) ----------
__global__ void __launch_bounds__(256) spmm_atomic_kernel(
    const int* __restrict__ indices, const float* __restrict__ values,
    const float* __restrict__ feat, float* __restrict__ out, int nnz, int n) {
  const long long gid = (long long)blockIdx.x * blockDim.x + threadIdx.x;
  const int lane = (int)(gid & 31);
  const long long e = gid >> 5;
  if (e >= nnz) return;
  const int r = indices[e];
  const int c = indices[(long long)nnz + e];
  const float v = values[e];
  const size_t bs = (size_t)n * FEAT_D;
  for (int b = 0; b < BATCH; ++b) {
    const float4 a = *(reinterpret_cast<const float4*>(feat + b * bs + (size_t)c * FEAT_D) + lane);
    float* dst = out + b * bs + (size_t)r * FEAT_D + (size_t)lane * 4;
    atomicAdd(dst + 0, v * a.x);
    atomicAdd(dst + 1, v * a.y);
    atomicAdd(dst + 2, v * a.z);
    atomicAdd(dst + 3, v * a.w);
  }
}

extern "C" void kernel_launch(void* const* d_in, const int* in_sizes, int n_in,
                              void* d_out, int out_size, void* d_ws, size_t ws_size,
                              hipStream_t stream) {
  const int* indices = (const int*)d_in[0];
  const float* values = (const float*)d_in[1];
  const float* feat = (const float*)d_in[3];
  float* out = (float*)d_out;

  const int nnz = in_sizes[1];
  const int n = out_size / (BATCH * FEAT_D);
  const int nb = (n + 255) >> RB_SHIFT;

  const int* rows = indices;
  const int* cols = indices + nnz;

  // workspace layout
  size_t off_offsets = 0;                                    // (n+1) ints
  size_t off_bcnt = off_offsets + (size_t)(n + 1) * 4;       // nb ints
  size_t off_bbase = off_bcnt + (size_t)nb * 4;              // nb+1 ints
  size_t off_gcur = off_bbase + (size_t)(nb + 1) * 4;        // nb ints
  size_t off_cv = (off_gcur + (size_t)nb * 4 + 255) & ~(size_t)255;   // nnz u64
  size_t off_packed = (off_cv + (size_t)nnz * 8 + 255) & ~(size_t)255;
  size_t packed_bytes = (size_t)n * BATCH * FEAT_D * 2;
  size_t cvb_bytes = (size_t)nnz * 8;
  size_t need = off_packed + (packed_bytes > cvb_bytes ? packed_bytes : cvb_bytes);

  if (ws_size < need || n > 65536 || nb > 256) {
    hipMemsetAsync(d_out, 0, (size_t)out_size * sizeof(float), stream);
    const long long total_threads = (long long)nnz * 32;
    const unsigned grid = (unsigned)((total_threads + 255) / 256);
    spmm_atomic_kernel<<<grid, 256, 0, stream>>>(indices, values, feat, out, nnz, n);
    return;
  }

  char* ws = (char*)d_ws;
  int* offsets = (int*)(ws + off_offsets);
  int* bcnt = (int*)(ws + off_bcnt);
  int* bbase = (int*)(ws + off_bbase);
  int* gcur = (int*)(ws + off_gcur);
  unsigned long long* cv = (unsigned long long*)(ws + off_cv);
  unsigned long long* cvb = (unsigned long long*)(ws + off_packed);  // aliases packed
  unsigned short* packed = (unsigned short*)(ws + off_packed);

  hipMemsetAsync(bcnt, 0, (size_t)nb * 4, stream);

  hist_bucket_kernel<<<512, 256, 0, stream>>>(rows, nnz, bcnt);
  scan_buckets_kernel<<<1, 256, 0, stream>>>(bcnt, nb, nnz, bbase, gcur, offsets, n);

  const int part_blocks = (nnz + PART_E - 1) / PART_E;
  partition_kernel<<<part_blocks, PART_T, 0, stream>>>(rows, cols, values, nnz, nb,
                                                       gcur, cvb);
  bucket_sort_kernel<<<nb, 256, 0, stream>>>(cvb, bbase, offsets, cv, n);

  // pack AFTER bucket_sort (cvb aliases packed region)
  const int pack_total = n * (BATCH * FEAT_D / 4);
  pack_kernel<<<(pack_total + 255) / 256, 256, 0, stream>>>(feat, packed, n);

  const unsigned seg_grid = (unsigned)(((long long)n * 64 + 255) / 256);
  spmm_seg_bf16_kernel<<<seg_grid, 256, 0, stream>>>(offsets, cv, packed, out, n);
}